// Round 5
// baseline (471.929 us; speedup 1.0000x reference)
//
#include <hip/hip_runtime.h>
#include <hip/hip_bf16.h>
#include <math.h>

typedef unsigned short ushort_t;
typedef __bf16 bf16x8 __attribute__((ext_vector_type(8)));
typedef float  f32x4  __attribute__((ext_vector_type(4)));

#define B_SZ   1024
#define SEQ    17
#define KVN    16
#define HDIM   256
#define NHEAD  8
#define DH     32
#define INF    150
#define OUTD   22
#define LN_EPS 1e-5f
#define N1     (B_SZ * SEQ)      // 17408
#define NN_    100000

// ---------------- workspace layout (bytes) ----------------
constexpr size_t SZ_H0    = (size_t)NN_ * 256 * 2;
constexpr size_t SZ_KV0   = (size_t)NN_ * 512 * 2;
constexpr size_t SZ_ROW   = (size_t)N1 * 256 * 2;
constexpr size_t OFF_H0   = 0;
constexpr size_t OFF_KV0  = OFF_H0 + SZ_H0;
constexpr size_t OFF_QKV1 = OFF_KV0;                       // alias (KV0 dead after A0)
constexpr size_t OFF_O1   = OFF_QKV1 + (size_t)N1 * 768 * 2;
constexpr size_t OFF_HA2  = OFF_O1 + (size_t)B_SZ * 256 * 2;
constexpr size_t OFF_H2   = OFF_HA2 + (size_t)B_SZ * 256 * 2;
constexpr size_t OFF_Q0   = OFF_KV0 + SZ_KV0;
constexpr size_t OFF_O0   = OFF_Q0 + SZ_ROW;
constexpr size_t OFF_H1   = OFF_O0;                        // alias (o0 dead after G3)
constexpr size_t OFF_HA   = OFF_O0 + SZ_ROW;
constexpr size_t OFF_IDS  = OFF_HA + SZ_ROW;
constexpr size_t OFF_WTIN = OFF_IDS + (size_t)N1 * 4;
constexpr size_t OFF_WKV0 = OFF_WTIN + 256 * 160 * 2;
constexpr size_t OFF_WQ0  = OFF_WKV0 + 512 * 256 * 2;
constexpr size_t OFF_WKVQ1= OFF_WQ0 + 256 * 256 * 2;
constexpr size_t OFF_WO0  = OFF_WKVQ1 + 768 * 256 * 2;
constexpr size_t OFF_WF0  = OFF_WO0 + 256 * 256 * 2;
constexpr size_t OFF_WO1  = OFF_WF0 + 256 * 256 * 2;
constexpr size_t OFF_WF1  = OFF_WO1 + 256 * 256 * 2;
constexpr size_t OFF_B1   = OFF_WF1 + 256 * 256 * 2;

__device__ __forceinline__ ushort_t f2bfu(float x) {
    __hip_bfloat16 h = __float2bfloat16(x);
    return *reinterpret_cast<ushort_t*>(&h);
}
__device__ __forceinline__ float bfu2f(ushort_t u) {
    __hip_bfloat16 h;
    *reinterpret_cast<ushort_t*>(&h) = u;
    return __bfloat162float(h);
}
__device__ __forceinline__ f32x4 mfma16(bf16x8 a, bf16x8 b, f32x4 c) {
    return __builtin_amdgcn_mfma_f32_16x16x32_bf16(a, b, c, 0, 0, 0);
}

// ---------------- prep (unchanged) ----------------
__global__ __launch_bounds__(256) void k_prep(
    const float* __restrict__ W_in, const float* __restrict__ Wqkv,
    const float* __restrict__ Wo, const float* __restrict__ Wf,
    const float* __restrict__ bqkv,
    const int* __restrict__ batch, const int* __restrict__ nbr2,
    char* __restrict__ ws) {
    const int job = blockIdx.y;
    const int idx = blockIdx.x * 256 + threadIdx.x;
    if (job == 11) {
        if (idx < N1) {
            int b = idx / SEQ, s = idx % SEQ;
            ((int*)(ws + OFF_IDS))[idx] = (s == 0) ? batch[b] : nbr2[b * KVN + s - 1];
        }
        return;
    }
    if (job == 12) {
        if (idx < 768) ((float*)(ws + OFF_B1))[idx] = bqkv[768 + ((idx + 256) % 768)];
        return;
    }
    const float* src = nullptr; ushort_t* dst = nullptr;
    int Kpad = 256, Kvalid = 256;
    switch (job) {
        case 0:  src = W_in;           dst = (ushort_t*)(ws + OFF_WTIN); Kpad = 160; Kvalid = 150; break;
        case 1:  src = Wqkv + 65536;   dst = (ushort_t*)(ws + OFF_WKV0); break;
        case 2:  src = Wqkv + 131072;  dst = (ushort_t*)(ws + OFF_WKV0) + 65536; break;
        case 3:  src = Wqkv;           dst = (ushort_t*)(ws + OFF_WQ0); break;
        case 4:  src = Wqkv + 262144;  dst = (ushort_t*)(ws + OFF_WKVQ1); break;
        case 5:  src = Wqkv + 327680;  dst = (ushort_t*)(ws + OFF_WKVQ1) + 65536; break;
        case 6:  src = Wqkv + 196608;  dst = (ushort_t*)(ws + OFF_WKVQ1) + 131072; break;
        case 7:  src = Wo;             dst = (ushort_t*)(ws + OFF_WO0); break;
        case 8:  src = Wo + 65536;     dst = (ushort_t*)(ws + OFF_WO1); break;
        case 9:  src = Wf;             dst = (ushort_t*)(ws + OFF_WF0); break;
        case 10: src = Wf + 65536;     dst = (ushort_t*)(ws + OFF_WF1); break;
    }
    const int total = 256 * Kpad;
    if (idx >= total) return;
    int n = idx / Kpad, k = idx % Kpad;
    dst[idx] = (k < Kvalid) ? f2bfu(src[(size_t)k * 256 + n]) : (ushort_t)0;
}

// ============== fused h0 + kv0, v3: 64-row tile, 52 KB LDS, 3 blocks/CU ======
__global__ __launch_bounds__(256, 3) void k_in_kv(
    const float* __restrict__ nf, const ushort_t* __restrict__ Wt_in,
    const float* __restrict__ b_in, const ushort_t* __restrict__ Wkv,
    const float* __restrict__ bqkv, ushort_t* __restrict__ h0,
    ushort_t* __restrict__ kv0) {
    __shared__ ushort_t Ah[64 * 256];        // 32 KB; XOR-swizzled h0 tile
    __shared__ ushort_t Bst[256][40];        // 20.5 KB; staging + epilogue bounce

    const int tid  = threadIdx.x;
    const int m0   = blockIdx.x * 64;
    const int lane = tid & 63, w = tid >> 6;
    const int lr = lane & 15, q4 = lane >> 4, lk = q4 * 8;

    // ---------------- phase 1: Ah = relu(nf_tile @ W_in + b_in) ----------------
    ushort_t (*Ain)[36] = reinterpret_cast<ushort_t (*)[36]>(Ah);  // corner of Ah
    const int rowA = tid >> 2, segA = tid & 3;
    const int rowS = tid >> 2, segS = tid & 3;   // B stage: 4 lanes per row

    auto loadA1 = [&](int s) -> int4 {
        int gm = m0 + rowA;
        bool v = gm < NN_; if (!v) gm = 0;
        int k0 = s * 32 + segA * 8;
        const float* ap = nf + (size_t)gm * INF + k0;
        ushort_t tmp[8];
        #pragma unroll
        for (int j = 0; j < 8; ++j)
            tmp[j] = (v && k0 + j < INF) ? f2bfu(ap[j]) : (ushort_t)0;
        return *reinterpret_cast<int4*>(tmp);
    };
    auto loadB1 = [&](int s) -> int4 {
        return *reinterpret_cast<const int4*>(
            Wt_in + (size_t)rowS * 160 + s * 32 + segS * 8);
    };

    int4 aP = loadA1(0);
    int4 bP = loadB1(0);
    // 256 threads stage [256 rows][32k] of B per step: 4 lanes/row covers 64 rows/iter? No:
    // rowS = tid>>2 covers rows 0..63 only; need 4 sub-iterations j for rows +64*j.
    // Rework: per step each thread loads 4 int4 (rows rowS + 64*j).
    int4 bPx[4];
    #pragma unroll
    for (int j = 0; j < 4; ++j)
        bPx[j] = *reinterpret_cast<const int4*>(
            Wt_in + (size_t)(rowS + 64 * j) * 160 + segS * 8);

    f32x4 acc1[4][4] = {};
    for (int s = 0; s < 5; ++s) {
        __syncthreads();
        *reinterpret_cast<int4*>(&Ain[rowA][segA * 8]) = aP;
        #pragma unroll
        for (int j = 0; j < 4; ++j)
            *reinterpret_cast<int4*>(&Bst[rowS + 64 * j][segS * 8]) = bPx[j];
        if (s < 4) {
            aP = loadA1(s + 1);
            #pragma unroll
            for (int j = 0; j < 4; ++j)
                bPx[j] = *reinterpret_cast<const int4*>(
                    Wt_in + (size_t)(rowS + 64 * j) * 160 + (s + 1) * 32 + segS * 8);
        }
        __syncthreads();
        bf16x8 a[4], b[4];
        #pragma unroll
        for (int mi = 0; mi < 4; ++mi)
            a[mi] = *reinterpret_cast<const bf16x8*>(&Ain[mi * 16 + lr][lk]);
        #pragma unroll
        for (int ni = 0; ni < 4; ++ni)
            b[ni] = *reinterpret_cast<const bf16x8*>(&Bst[w * 64 + ni * 16 + lr][lk]);
        #pragma unroll
        for (int mi = 0; mi < 4; ++mi)
            #pragma unroll
            for (int ni = 0; ni < 4; ++ni)
                acc1[mi][ni] = mfma16(a[mi], b[ni], acc1[mi][ni]);
    }
    __syncthreads();                    // all reads of Ain/Bst done before Ah overwrite
    // bias + relu -> Ah (XOR-swizzled)
    #pragma unroll
    for (int ni = 0; ni < 4; ++ni) {
        int col = w * 64 + ni * 16 + lr;
        float bb = b_in[col];
        #pragma unroll
        for (int mi = 0; mi < 4; ++mi)
            #pragma unroll
            for (int r = 0; r < 4; ++r) {
                int row = mi * 16 + q4 * 4 + r;
                Ah[row * 256 + (col ^ ((row & 7) << 3))] =
                    f2bfu(fmaxf(acc1[mi][ni][r] + bb, 0.f));
            }
    }
    __syncthreads();
    // h0 tile -> global
    #pragma unroll
    for (int i = 0; i < 8; ++i) {
        int flat = tid + i * 256;                 // 64 rows x 32 chunks
        int row = flat >> 5, ch = flat & 31;
        if (m0 + row < NN_)
            *reinterpret_cast<int4*>(h0 + (size_t)(m0 + row) * 256 + ch * 8) =
                *reinterpret_cast<const int4*>(&Ah[row * 256 + (ch ^ (row & 7)) * 8]);
    }

    // ---------------- phase 2: kv = Ah @ Wkv, two 256-col halves ----------------
    for (int h = 0; h < 2; ++h) {
        int4 b2P[4];
        #pragma unroll
        for (int j = 0; j < 4; ++j)
            b2P[j] = *reinterpret_cast<const int4*>(
                Wkv + (size_t)(h * 256 + rowS + 64 * j) * 256 + segS * 8);

        f32x4 acc2[4][4] = {};
        for (int s = 0; s < 8; ++s) {
            __builtin_amdgcn_s_barrier();         // prior readers of Bst done
            #pragma unroll
            for (int j = 0; j < 4; ++j)
                *reinterpret_cast<int4*>(&Bst[rowS + 64 * j][segS * 8]) = b2P[j];
            if (s < 7) {
                #pragma unroll
                for (int j = 0; j < 4; ++j)
                    b2P[j] = *reinterpret_cast<const int4*>(
                        Wkv + (size_t)(h * 256 + rowS + 64 * j) * 256 + (s + 1) * 32 + segS * 8);
            }
            asm volatile("s_waitcnt lgkmcnt(0)" ::: "memory");
            __builtin_amdgcn_s_barrier();         // writes visible; prefetch stays in flight
            bf16x8 a[4], b[4];
            #pragma unroll
            for (int mi = 0; mi < 4; ++mi) {
                int row = mi * 16 + lr;
                int chunk = (s * 4 + q4) ^ (row & 7);
                a[mi] = *reinterpret_cast<const bf16x8*>(&Ah[row * 256 + chunk * 8]);
            }
            #pragma unroll
            for (int ni = 0; ni < 4; ++ni)
                b[ni] = *reinterpret_cast<const bf16x8*>(&Bst[w * 64 + ni * 16 + lr][lk]);
            #pragma unroll
            for (int mi = 0; mi < 4; ++mi)
                #pragma unroll
                for (int ni = 0; ni < 4; ++ni)
                    acc2[mi][ni] = mfma16(a[mi], b[ni], acc2[mi][ni]);
        }
        __syncthreads();                           // final readers done; Bst reusable
        // epilogue: two 128-col sub-passes bounced through Bst as [64][132]
        ushort_t (*BE)[132] = reinterpret_cast<ushort_t (*)[132]>(&Bst[0][0]);
        #pragma unroll
        for (int sub = 0; sub < 2; ++sub) {
            if ((w >> 1) == sub) {
                int cb = (w & 1) * 64;
                #pragma unroll
                for (int ni = 0; ni < 4; ++ni) {
                    int coll = cb + ni * 16 + lr;
                    float bb = bqkv[256 + h * 256 + sub * 128 + coll];
                    #pragma unroll
                    for (int mi = 0; mi < 4; ++mi)
                        #pragma unroll
                        for (int r = 0; r < 4; ++r) {
                            int row = mi * 16 + q4 * 4 + r;
                            BE[row][coll] = f2bfu(acc2[mi][ni][r] + bb);
                        }
                }
            }
            __syncthreads();
            #pragma unroll
            for (int i = 0; i < 4; ++i) {
                int flat = tid + i * 256;          // 64 rows x 16 chunks
                int row = flat >> 4, ch = flat & 15;
                if (m0 + row < NN_)
                    *reinterpret_cast<int4*>(
                        kv0 + (size_t)(m0 + row) * 512 + h * 256 + sub * 128 + ch * 8) =
                        *reinterpret_cast<const int4*>(&BE[row][ch * 8]);
            }
            __syncthreads();
        }
    }
}

// ---------------- generic 64x64 MFMA GEMM (Q0, QKV1), reg-prefetch ----------
template<bool RELU>
__global__ __launch_bounds__(256) void gemm64(
    const ushort_t* __restrict__ Asrc, const ushort_t* __restrict__ Bt,
    const float* __restrict__ biasN, ushort_t* __restrict__ out,
    int M, int Ksteps, int lda, int ldb, int ldo,
    const int* __restrict__ arid) {
    __shared__ ushort_t Al[64][40];
    __shared__ ushort_t Bl[64][40];
    const int tid = threadIdx.x;
    const int m0 = blockIdx.x * 64, n0 = blockIdx.y * 64;
    const int lane = tid & 63, w = tid >> 6, wm = w >> 1, wn = w & 1;
    const int srow = tid >> 2, sch = tid & 3;
    const int gmi = m0 + srow;
    const bool valid = gmi < M;
    const int gr = valid ? (arid ? arid[gmi] : gmi) : 0;
    const ushort_t* arow = Asrc + (size_t)gr * lda + sch * 8;
    const ushort_t* brow = Bt + (size_t)(n0 + srow) * ldb + sch * 8;

    int4 aP = {0, 0, 0, 0};
    if (valid) aP = *reinterpret_cast<const int4*>(arow);
    int4 bP = *reinterpret_cast<const int4*>(brow);

    f32x4 acc[2][2] = {};
    for (int s = 0; s < Ksteps; ++s) {
        __syncthreads();
        *reinterpret_cast<int4*>(&Al[srow][sch * 8]) = aP;
        *reinterpret_cast<int4*>(&Bl[srow][sch * 8]) = bP;
        if (s + 1 < Ksteps) {
            if (valid) aP = *reinterpret_cast<const int4*>(arow + (s + 1) * 32);
            bP = *reinterpret_cast<const int4*>(brow + (s + 1) * 32);
        }
        __syncthreads();
        const int lr = lane & 15, lk = (lane >> 4) * 8;
        bf16x8 a0 = *reinterpret_cast<const bf16x8*>(&Al[wm * 32 + lr][lk]);
        bf16x8 a1 = *reinterpret_cast<const bf16x8*>(&Al[wm * 32 + 16 + lr][lk]);
        bf16x8 b0 = *reinterpret_cast<const bf16x8*>(&Bl[wn * 32 + lr][lk]);
        bf16x8 b1 = *reinterpret_cast<const bf16x8*>(&Bl[wn * 32 + 16 + lr][lk]);
        acc[0][0] = mfma16(a0, b0, acc[0][0]);
        acc[0][1] = mfma16(a0, b1, acc[0][1]);
        acc[1][0] = mfma16(a1, b0, acc[1][0]);
        acc[1][1] = mfma16(a1, b1, acc[1][1]);
    }
    #pragma unroll
    for (int mi = 0; mi < 2; ++mi)
        #pragma unroll
        for (int ni = 0; ni < 2; ++ni)
            #pragma unroll
            for (int r = 0; r < 4; ++r) {
                int m = m0 + wm * 32 + mi * 16 + ((lane >> 4) << 2) + r;
                int n = n0 + wn * 32 + ni * 16 + (lane & 15);
                if (m < M) {
                    float v = acc[mi][ni][r] + biasN[n];
                    if (RELU) v = fmaxf(v, 0.f);
                    out[(size_t)m * ldo + n] = f2bfu(v);
                }
            }
}

// ---------------- 32x256 GEMM + bias + residual + LayerNorm, A resident -----
__global__ __launch_bounds__(256) void gemm_ln(
    const ushort_t* __restrict__ A, const ushort_t* __restrict__ Bt,
    const float* __restrict__ biasN,
    const ushort_t* __restrict__ resmat, const int* __restrict__ residx, int rstride,
    const float* __restrict__ lng, const float* __restrict__ lnb,
    ushort_t* __restrict__ out, int M) {
    __shared__ union {
        struct { ushort_t Al[32][264]; ushort_t Bl[256][40]; } s;   // 37.4 KB
        struct { float xr[32][260]; float mrow[32]; float rrow[32]; int sidx[32]; } e;
    } sm;
    const int tid = threadIdx.x;
    const int m0 = blockIdx.x * 32;
    const int lane = tid & 63, w = tid >> 6;
    const int lr = lane & 15, lk = (lane >> 4) * 8;

    // stage full 32x256 A tile once
    #pragma unroll
    for (int j = 0; j < 4; ++j) {
        int flat = tid + j * 256;
        int row = flat >> 5, ch = flat & 31;
        *reinterpret_cast<int4*>(&sm.s.Al[row][ch * 8]) =
            *reinterpret_cast<const int4*>(A + (size_t)(m0 + row) * 256 + ch * 8);
    }
    const ushort_t* brow = Bt + (size_t)tid * 256;
    int4 bP[4];
    #pragma unroll
    for (int j = 0; j < 4; ++j) bP[j] = *reinterpret_cast<const int4*>(brow + j * 8);

    f32x4 acc[2][4] = {};
    for (int s = 0; s < 8; ++s) {
        __syncthreads();
        #pragma unroll
        for (int j = 0; j < 4; ++j)
            *reinterpret_cast<int4*>(&sm.s.Bl[tid][j * 8]) = bP[j];
        if (s < 7) {
            #pragma unroll
            for (int j = 0; j < 4; ++j)
                bP[j] = *reinterpret_cast<const int4*>(brow + (s + 1) * 32 + j * 8);
        }
        __syncthreads();
        bf16x8 a0 = *reinterpret_cast<const bf16x8*>(&sm.s.Al[lr][s * 32 + lk]);
        bf16x8 a1 = *reinterpret_cast<const bf16x8*>(&sm.s.Al[16 + lr][s * 32 + lk]);
        #pragma unroll
        for (int ni = 0; ni < 4; ++ni) {
            bf16x8 b = *reinterpret_cast<const bf16x8*>(&sm.s.Bl[w * 64 + ni * 16 + lr][lk]);
            acc[0][ni] = mfma16(a0, b, acc[0][ni]);
            acc[1][ni] = mfma16(a1, b, acc[1][ni]);
        }
    }
    __syncthreads();
    if (tid < 32) sm.e.sidx[tid] = residx ? residx[m0 + tid] : (m0 + tid) * rstride;
    #pragma unroll
    for (int mi = 0; mi < 2; ++mi)
        #pragma unroll
        for (int ni = 0; ni < 4; ++ni)
            #pragma unroll
            for (int r = 0; r < 4; ++r) {
                int rl = mi * 16 + ((lane >> 4) << 2) + r;
                int cl = w * 64 + ni * 16 + (lane & 15);
                sm.e.xr[rl][cl] = acc[mi][ni][r];
            }
    __syncthreads();
    {
        float bn = biasN[tid];
        for (int r = 0; r < 32; ++r)
            sm.e.xr[r][tid] += bn + bfu2f(resmat[(size_t)sm.e.sidx[r] * 256 + tid]);
    }
    __syncthreads();
    {
        for (int rr = w * 8; rr < w * 8 + 8; ++rr) {
            float4 v = *reinterpret_cast<const float4*>(&sm.e.xr[rr][lane * 4]);
            float s1 = v.x + v.y + v.z + v.w;
            float s2 = v.x * v.x + v.y * v.y + v.z * v.z + v.w * v.w;
            #pragma unroll
            for (int off = 32; off > 0; off >>= 1) {
                s1 += __shfl_xor(s1, off);
                s2 += __shfl_xor(s2, off);
            }
            if (lane == 0) {
                float m = s1 * (1.f / 256.f);
                float var = s2 * (1.f / 256.f) - m * m;
                sm.e.mrow[rr] = m;
                sm.e.rrow[rr] = rsqrtf(var + LN_EPS);
            }
        }
    }
    __syncthreads();
    {
        float g = lng[tid], b = lnb[tid];
        for (int r = 0; r < 32; ++r) {
            float v = (sm.e.xr[r][tid] - sm.e.mrow[r]) * sm.e.rrow[r] * g + b;
            out[(size_t)(m0 + r) * 256 + tid] = f2bfu(v);
        }
    }
}

// ---------------- attention: one wave per group (unchanged) ----------------
__global__ __launch_bounds__(256) void attn_wave(
    const ushort_t* __restrict__ q_all, int qld, int qoff, int qstride,
    const ushort_t* __restrict__ kv_all, int kvld, int koff, int voff,
    const int* __restrict__ kvidx, int ngroups, ushort_t* __restrict__ o_out) {
    __shared__ ushort_t KL[4][KVN][264];
    __shared__ ushort_t VL[4][KVN][264];
    const int w = threadIdx.x >> 6, lane = threadIdx.x & 63;
    const int g = blockIdx.x * 4 + w;
    if (g >= ngroups) return;

    int idx16 = 0;
    if (lane < KVN)
        idx16 = kvidx ? kvidx[g * KVN + lane] : g * SEQ + 1 + lane;

    float qv[4];
    {
        uint2 u = *reinterpret_cast<const uint2*>(
            q_all + (size_t)g * qstride * qld + qoff + lane * 4);
        qv[0] = bfu2f((ushort_t)(u.x & 0xffff));
        qv[1] = bfu2f((ushort_t)(u.x >> 16));
        qv[2] = bfu2f((ushort_t)(u.y & 0xffff));
        qv[3] = bfu2f((ushort_t)(u.y >> 16));
    }
    {
        const int r = lane & 15, qtr = lane >> 4;
        int rid = __shfl(idx16, r);
        const ushort_t* kb = kv_all + (size_t)rid * kvld + koff;
        const ushort_t* vb = kv_all + (size_t)rid * kvld + voff;
        #pragma unroll
        for (int j = 0; j < 8; ++j) {
            int c8 = (qtr * 8 + j) * 8;
            *reinterpret_cast<int4*>(&KL[w][r][c8]) = *reinterpret_cast<const int4*>(kb + c8);
            *reinterpret_cast<int4*>(&VL[w][r][c8]) = *reinterpret_cast<const int4*>(vb + c8);
        }
    }
    float att[KVN];
    #pragma unroll
    for (int k = 0; k < KVN; ++k) {
        uint2 u = *reinterpret_cast<const uint2*>(&KL[w][k][lane * 4]);
        float p = qv[0] * bfu2f((ushort_t)(u.x & 0xffff))
                + qv[1] * bfu2f((ushort_t)(u.x >> 16))
                + qv[2] * bfu2f((ushort_t)(u.y & 0xffff))
                + qv[3] * bfu2f((ushort_t)(u.y >> 16));
        p += __shfl_xor(p, 1);
        p += __shfl_xor(p, 2);
        p += __shfl_xor(p, 4);
        att[k] = p * 0.17677669529663687f;
    }
    float m = att[0];
    #pragma unroll
    for (int k = 1; k < KVN; ++k) m = fmaxf(m, att[k]);
    float sum = 0.f;
    #pragma unroll
    for (int k = 0; k < KVN; ++k) { att[k] = __expf(att[k] - m); sum += att[k]; }
    float inv = 1.f / sum;
    float o[4] = {0.f, 0.f, 0.f, 0.f};
    #pragma unroll
    for (int k = 0; k < KVN; ++k) {
        uint2 u = *reinterpret_cast<const uint2*>(&VL[w][k][lane * 4]);
        float a = att[k] * inv;
        o[0] += a * bfu2f((ushort_t)(u.x & 0xffff));
        o[1] += a * bfu2f((ushort_t)(u.x >> 16));
        o[2] += a * bfu2f((ushort_t)(u.y & 0xffff));
        o[3] += a * bfu2f((ushort_t)(u.y >> 16));
    }
    uint2 r;
    r.x = (unsigned)f2bfu(o[0]) | ((unsigned)f2bfu(o[1]) << 16);
    r.y = (unsigned)f2bfu(o[2]) | ((unsigned)f2bfu(o[3]) << 16);
    *reinterpret_cast<uint2*>(o_out + (size_t)g * 256 + lane * 4) = r;
}

// ---------------- output head (unchanged) ----------------
__global__ __launch_bounds__(64) void k_out(
    const ushort_t* __restrict__ h2, const float* __restrict__ W_out,
    const float* __restrict__ b_out, float* __restrict__ out) {
    const int b = blockIdx.x, j = threadIdx.x;
    __shared__ float xr[HDIM];
    for (int k = j; k < HDIM; k += 64) xr[k] = bfu2f(h2[(size_t)b * HDIM + k]);
    __syncthreads();
    float logit = -1e30f;
    if (j < OUTD) {
        float acc = b_out[j];
        for (int k = 0; k < HDIM; ++k) acc += xr[k] * W_out[k * OUTD + j];
        logit = acc;
    }
    float m = logit;
    #pragma unroll
    for (int off = 32; off > 0; off >>= 1) m = fmaxf(m, __shfl_xor(m, off));
    float e = (j < OUTD) ? __expf(logit - m) : 0.f;
    float s = e;
    #pragma unroll
    for (int off = 32; off > 0; off >>= 1) s += __shfl_xor(s, off);
    if (j < OUTD) out[(size_t)b * OUTD + j] = e / s;
}

extern "C" void kernel_launch(void* const* d_in, const int* in_sizes, int n_in,
                              void* d_out, int out_size, void* d_ws, size_t ws_size,
                              hipStream_t stream) {
    const float* nf    = (const float*)d_in[0];
    const int*   batch = (const int*)d_in[1];
    const int*   nbr2  = (const int*)d_in[2];
    const int*   nbr1  = (const int*)d_in[3];
    const float* W_in  = (const float*)d_in[4];
    const float* b_in  = (const float*)d_in[5];
    const float* Wqkv  = (const float*)d_in[6];
    const float* bqkv  = (const float*)d_in[7];
    const float* Wo    = (const float*)d_in[8];
    const float* bo    = (const float*)d_in[9];
    const float* Wf    = (const float*)d_in[10];
    const float* bf    = (const float*)d_in[11];
    const float* ln_g  = (const float*)d_in[12];
    const float* ln_b  = (const float*)d_in[13];
    const float* W_out = (const float*)d_in[14];
    const float* b_out = (const float*)d_in[15];
    float* out = (float*)d_out;
    char* ws = (char*)d_ws;

    ushort_t* h0   = (ushort_t*)(ws + OFF_H0);
    ushort_t* kv0  = (ushort_t*)(ws + OFF_KV0);
    ushort_t* q0   = (ushort_t*)(ws + OFF_Q0);
    ushort_t* o0   = (ushort_t*)(ws + OFF_O0);
    ushort_t* ha   = (ushort_t*)(ws + OFF_HA);
    ushort_t* h1   = (ushort_t*)(ws + OFF_H1);
    ushort_t* qkv1 = (ushort_t*)(ws + OFF_QKV1);
    ushort_t* o1   = (ushort_t*)(ws + OFF_O1);
    ushort_t* ha2  = (ushort_t*)(ws + OFF_HA2);
    ushort_t* h2   = (ushort_t*)(ws + OFF_H2);
    const int* ids1 = (const int*)(ws + OFF_IDS);

    hipLaunchKernelGGL(k_prep, dim3(256, 13), dim3(256), 0, stream,
                       W_in, Wqkv, Wo, Wf, bqkv, batch, nbr2, ws);
    // fused G1+G2 v3: 64-row tiles, 3 blocks/CU
    hipLaunchKernelGGL(k_in_kv, dim3(1563), dim3(256), 0, stream,
                       nf, (const ushort_t*)(ws + OFF_WTIN), b_in,
                       (const ushort_t*)(ws + OFF_WKV0), bqkv, h0, kv0);
    // Q0 = h0[ids1] @ Wq0 + bq0
    hipLaunchKernelGGL((gemm64<false>), dim3(272, 4), dim3(256), 0, stream,
                       h0, (const ushort_t*)(ws + OFF_WQ0), bqkv, q0,
                       N1, 8, 256, 256, 256, ids1);
    // A0: 17408 groups, one wave each
    hipLaunchKernelGGL(attn_wave, dim3(N1 / 4), dim3(256), 0, stream,
                       q0, 256, 0, 1, kv0, 512, 0, 256, nbr1, N1, o0);
    // G3: ha = LN(o0 @ Wo0 + bo0 + h0[ids1])
    hipLaunchKernelGGL(gemm_ln, dim3(544), dim3(256), 0, stream,
                       o0, (const ushort_t*)(ws + OFF_WO0), bo,
                       h0, ids1, 1, ln_g, ln_b, ha, N1);
    // G4: h1 = LN(ha @ Wf0 + bf0 + ha)
    hipLaunchKernelGGL(gemm_ln, dim3(544), dim3(256), 0, stream,
                       ha, (const ushort_t*)(ws + OFF_WF0), bf,
                       ha, (const int*)nullptr, 1, ln_g + 256, ln_b + 256, h1, N1);
    // G5: QKV1 = h1 @ [Wk1|Wv1|Wq1] + b
    hipLaunchKernelGGL((gemm64<false>), dim3(272, 12), dim3(256), 0, stream,
                       h1, (const ushort_t*)(ws + OFF_WKVQ1),
                       (const float*)(ws + OFF_B1), qkv1,
                       N1, 8, 256, 256, 768, (const int*)nullptr);
    // A1: 1024 groups
    hipLaunchKernelGGL(attn_wave, dim3(B_SZ / 4), dim3(256), 0, stream,
                       qkv1, 768, 512, 17, qkv1, 768, 0, 256,
                       (const int*)nullptr, B_SZ, o1);
    // G6: ha2 = LN(o1 @ Wo1 + bo1 + h1[17b])
    hipLaunchKernelGGL(gemm_ln, dim3(32), dim3(256), 0, stream,
                       o1, (const ushort_t*)(ws + OFF_WO1), bo + 256,
                       h1, (const int*)nullptr, 17, ln_g + 512, ln_b + 512, ha2, B_SZ);
    // G7: h2 = LN(ha2 @ Wf1 + bf1 + ha2)
    hipLaunchKernelGGL(gemm_ln, dim3(32), dim3(256), 0, stream,
                       ha2, (const ushort_t*)(ws + OFF_WF1), bf + 256,
                       ha2, (const int*)nullptr, 1, ln_g + 768, ln_b + 768, h2, B_SZ);
    hipLaunchKernelGGL(k_out, dim3(B_SZ), dim3(64), 0, stream,
                       h2, W_out, b_out, out);
}

// Round 6
// 337.142 us; speedup vs baseline: 1.3998x; 1.3998x over previous
//
#include <hip/hip_runtime.h>
#include <hip/hip_bf16.h>
#include <math.h>

typedef unsigned short ushort_t;
typedef __bf16 bf16x8 __attribute__((ext_vector_type(8)));
typedef float  f32x4  __attribute__((ext_vector_type(4)));

#define B_SZ   1024
#define SEQ    17
#define KVN    16
#define HDIM   256
#define NHEAD  8
#define DH     32
#define INF    150
#define OUTD   22
#define LN_EPS 1e-5f
#define N1     (B_SZ * SEQ)      // 17408
#define NN_    100000
#define NKVBLK 1563
#define NHQBLK 272               // 17408 / 64 exactly

// ---------------- workspace layout (bytes) ----------------
constexpr size_t SZ_H0    = (size_t)NN_ * 256 * 2;
constexpr size_t SZ_KV0   = (size_t)NN_ * 512 * 2;
constexpr size_t SZ_ROW   = (size_t)N1 * 256 * 2;
constexpr size_t OFF_HQ   = 0;                             // 17408x256 bf16 (in old h0 slot)
constexpr size_t OFF_KV0  = OFF_HQ + SZ_H0;
constexpr size_t OFF_QKV1 = OFF_KV0;                       // alias (KV0 dead after A0)
constexpr size_t OFF_O1   = OFF_QKV1 + (size_t)N1 * 768 * 2;
constexpr size_t OFF_HA2  = OFF_O1 + (size_t)B_SZ * 256 * 2;
constexpr size_t OFF_H2   = OFF_HA2 + (size_t)B_SZ * 256 * 2;
constexpr size_t OFF_Q0   = OFF_KV0 + SZ_KV0;
constexpr size_t OFF_O0   = OFF_Q0 + SZ_ROW;
constexpr size_t OFF_H1   = OFF_O0;                        // alias (o0 dead after G3)
constexpr size_t OFF_HA   = OFF_O0 + SZ_ROW;
constexpr size_t OFF_IDS  = OFF_HA + SZ_ROW;
constexpr size_t OFF_WTIN = OFF_IDS + (size_t)N1 * 4;
constexpr size_t OFF_WKV0 = OFF_WTIN + 256 * 160 * 2;
constexpr size_t OFF_WQ0  = OFF_WKV0 + 512 * 256 * 2;
constexpr size_t OFF_WKVQ1= OFF_WQ0 + 256 * 256 * 2;
constexpr size_t OFF_WO0  = OFF_WKVQ1 + 768 * 256 * 2;
constexpr size_t OFF_WF0  = OFF_WO0 + 256 * 256 * 2;
constexpr size_t OFF_WO1  = OFF_WF0 + 256 * 256 * 2;
constexpr size_t OFF_WF1  = OFF_WO1 + 256 * 256 * 2;
constexpr size_t OFF_B1   = OFF_WF1 + 256 * 256 * 2;

__device__ __forceinline__ ushort_t f2bfu(float x) {
    __hip_bfloat16 h = __float2bfloat16(x);
    return *reinterpret_cast<ushort_t*>(&h);
}
__device__ __forceinline__ float bfu2f(ushort_t u) {
    __hip_bfloat16 h;
    *reinterpret_cast<ushort_t*>(&h) = u;
    return __bfloat162float(h);
}
__device__ __forceinline__ f32x4 mfma16(bf16x8 a, bf16x8 b, f32x4 c) {
    return __builtin_amdgcn_mfma_f32_16x16x32_bf16(a, b, c, 0, 0, 0);
}

// ---------------- prep (unchanged) ----------------
__global__ __launch_bounds__(256) void k_prep(
    const float* __restrict__ W_in, const float* __restrict__ Wqkv,
    const float* __restrict__ Wo, const float* __restrict__ Wf,
    const float* __restrict__ bqkv,
    const int* __restrict__ batch, const int* __restrict__ nbr2,
    char* __restrict__ ws) {
    const int job = blockIdx.y;
    const int idx = blockIdx.x * 256 + threadIdx.x;
    if (job == 11) {
        if (idx < N1) {
            int b = idx / SEQ, s = idx % SEQ;
            ((int*)(ws + OFF_IDS))[idx] = (s == 0) ? batch[b] : nbr2[b * KVN + s - 1];
        }
        return;
    }
    if (job == 12) {
        if (idx < 768) ((float*)(ws + OFF_B1))[idx] = bqkv[768 + ((idx + 256) % 768)];
        return;
    }
    const float* src = nullptr; ushort_t* dst = nullptr;
    int Kpad = 256, Kvalid = 256;
    switch (job) {
        case 0:  src = W_in;           dst = (ushort_t*)(ws + OFF_WTIN); Kpad = 160; Kvalid = 150; break;
        case 1:  src = Wqkv + 65536;   dst = (ushort_t*)(ws + OFF_WKV0); break;
        case 2:  src = Wqkv + 131072;  dst = (ushort_t*)(ws + OFF_WKV0) + 65536; break;
        case 3:  src = Wqkv;           dst = (ushort_t*)(ws + OFF_WQ0); break;
        case 4:  src = Wqkv + 262144;  dst = (ushort_t*)(ws + OFF_WKVQ1); break;
        case 5:  src = Wqkv + 327680;  dst = (ushort_t*)(ws + OFF_WKVQ1) + 65536; break;
        case 6:  src = Wqkv + 196608;  dst = (ushort_t*)(ws + OFF_WKVQ1) + 131072; break;
        case 7:  src = Wo;             dst = (ushort_t*)(ws + OFF_WO0); break;
        case 8:  src = Wo + 65536;     dst = (ushort_t*)(ws + OFF_WO1); break;
        case 9:  src = Wf;             dst = (ushort_t*)(ws + OFF_WF0); break;
        case 10: src = Wf + 65536;     dst = (ushort_t*)(ws + OFF_WF1); break;
    }
    const int total = 256 * Kpad;
    if (idx >= total) return;
    int n = idx / Kpad, k = idx % Kpad;
    dst[idx] = (k < Kvalid) ? f2bfu(src[(size_t)k * 256 + n]) : (ushort_t)0;
}

// ============== fused: kv0 (blocks 0..1562) + hq/q0 (blocks 1563..1834) ======
// Barrier-free K-loops: A resident in LDS, B global->register per wave
// (each wave owns a disjoint 64-col slice of N -> no redundant loads).
__global__ __launch_bounds__(256) void k_fused(
    const float* __restrict__ nf,
    const ushort_t* __restrict__ Wt_in, const float* __restrict__ b_in,
    const ushort_t* __restrict__ Wkv, const ushort_t* __restrict__ Wq,
    const float* __restrict__ bqkv, const int* __restrict__ ids1,
    ushort_t* __restrict__ kv0, ushort_t* __restrict__ hq,
    ushort_t* __restrict__ q0) {
    __shared__ ushort_t Ah[64 * 256];        // 32 KB; XOR-swizzled A tile
    __shared__ ushort_t Sh[4][32][72];       // 18.4 KB; wave-private epilogue bounce
    const int tid = threadIdx.x;
    const bool iskv = blockIdx.x < NKVBLK;
    const int m0 = (iskv ? blockIdx.x : blockIdx.x - NKVBLK) * 64;
    const int lane = tid & 63, w = tid >> 6;      // wave w owns cols w*64..+63
    const int lr = lane & 15, q4 = lane >> 4, lk = q4 * 8;

    // ---- stage A: 64 rows x 160 cols, f32->bf16, into Astage (aliases Ah) ----
    {
        ushort_t (*Astage)[168] = reinterpret_cast<ushort_t (*)[168]>(Ah);
        #pragma unroll
        for (int i = 0; i < 5; ++i) {
            int flat = tid + i * 256;             // 1280 chunks = 64 rows x 20
            int row = flat / 20, ch = flat % 20;
            int gm; bool valid;
            if (iskv) { gm = m0 + row; valid = gm < NN_; if (!valid) gm = 0; }
            else      { gm = ids1[m0 + row]; valid = true; }
            const float* ap = nf + (size_t)gm * INF + ch * 8;
            ushort_t tmp[8];
            if (valid && ch < 18) {
                #pragma unroll
                for (int j = 0; j < 4; ++j) {
                    float2 f = *reinterpret_cast<const float2*>(ap + j * 2);
                    tmp[j * 2] = f2bfu(f.x); tmp[j * 2 + 1] = f2bfu(f.y);
                }
            } else {
                #pragma unroll
                for (int j = 0; j < 8; ++j) {
                    int k = ch * 8 + j;
                    tmp[j] = (valid && k < INF) ? f2bfu(ap[j]) : (ushort_t)0;
                }
            }
            *reinterpret_cast<int4*>(&Astage[row][ch * 8]) = *reinterpret_cast<int4*>(tmp);
        }
    }
    __syncthreads();

    // ---- phase 1: acc = A @ W_in^T-slice (K=160), NO barriers ----
    f32x4 acc[4][4] = {};
    {
        ushort_t (*Astage)[168] = reinterpret_cast<ushort_t (*)[168]>(Ah);
        #pragma unroll 2
        for (int s = 0; s < 5; ++s) {
            bf16x8 a[4], b[4];
            #pragma unroll
            for (int mi = 0; mi < 4; ++mi)
                a[mi] = *reinterpret_cast<const bf16x8*>(&Astage[mi * 16 + lr][s * 32 + lk]);
            #pragma unroll
            for (int ni = 0; ni < 4; ++ni)
                b[ni] = *reinterpret_cast<const bf16x8*>(
                    Wt_in + (size_t)(w * 64 + ni * 16 + lr) * 160 + s * 32 + lk);
            #pragma unroll
            for (int mi = 0; mi < 4; ++mi)
                #pragma unroll
                for (int ni = 0; ni < 4; ++ni)
                    acc[mi][ni] = mfma16(a[mi], b[ni], acc[mi][ni]);
        }
    }
    __syncthreads();          // all Astage reads complete before Ah overwrite

    // ---- bias + relu -> Ah (XOR-swizzled; formula verified in r5) ----
    #pragma unroll
    for (int ni = 0; ni < 4; ++ni) {
        int col = w * 64 + ni * 16 + lr;
        float bb = b_in[col];
        #pragma unroll
        for (int mi = 0; mi < 4; ++mi)
            #pragma unroll
            for (int r = 0; r < 4; ++r) {
                int row = mi * 16 + q4 * 4 + r;
                Ah[row * 256 + (col ^ ((row & 7) << 3))] =
                    f2bfu(fmaxf(acc[mi][ni][r] + bb, 0.f));
            }
    }
    __syncthreads();

    // hq blocks also persist the relu'd tile (G3 residual + nothing else needs h0)
    if (!iskv) {
        #pragma unroll
        for (int i = 0; i < 8; ++i) {
            int flat = tid + i * 256;
            int row = flat >> 5, ch = flat & 31;
            *reinterpret_cast<int4*>(hq + (size_t)(m0 + row) * 256 + ch * 8) =
                *reinterpret_cast<const int4*>(&Ah[row * 256 + (ch ^ (row & 7)) * 8]);
        }
    }

    // ---- phase 2: out = Ah @ B (K=256), NO barriers (Ah read-only) ----
    const int nh = iskv ? 2 : 1;
    for (int h = 0; h < nh; ++h) {
        const ushort_t* Bm = iskv ? (Wkv + (size_t)h * 256 * 256) : Wq;
        const float* bias = iskv ? (bqkv + 256 + h * 256) : bqkv;   // k@256,v@512; q@0
        f32x4 acc2[4][4] = {};
        #pragma unroll 2
        for (int s = 0; s < 8; ++s) {
            bf16x8 a[4], b[4];
            #pragma unroll
            for (int mi = 0; mi < 4; ++mi) {
                int row = mi * 16 + lr;
                int chunk = (s * 4 + q4) ^ (row & 7);
                a[mi] = *reinterpret_cast<const bf16x8*>(&Ah[row * 256 + chunk * 8]);
            }
            #pragma unroll
            for (int ni = 0; ni < 4; ++ni)
                b[ni] = *reinterpret_cast<const bf16x8*>(
                    Bm + (size_t)(w * 64 + ni * 16 + lr) * 256 + s * 32 + lk);
            #pragma unroll
            for (int mi = 0; mi < 4; ++mi)
                #pragma unroll
                for (int ni = 0; ni < 4; ++ni)
                    acc2[mi][ni] = mfma16(a[mi], b[ni], acc2[mi][ni]);
        }
        float bl[4];
        #pragma unroll
        for (int ni = 0; ni < 4; ++ni) bl[ni] = bias[w * 64 + ni * 16 + lr];
        ushort_t* outp = iskv ? kv0 : q0;
        const int ldo = iskv ? 512 : 256;
        const int coff = (iskv ? h * 256 : 0) + w * 64;
        // wave-private bounce: 2 parts of 32 rows, zero barriers
        #pragma unroll
        for (int part = 0; part < 2; ++part) {
            #pragma unroll
            for (int mi2 = 0; mi2 < 2; ++mi2) {
                int mi = part * 2 + mi2;
                #pragma unroll
                for (int ni = 0; ni < 4; ++ni)
                    #pragma unroll
                    for (int r = 0; r < 4; ++r)
                        Sh[w][mi2 * 16 + q4 * 4 + r][ni * 16 + lr] =
                            f2bfu(acc2[mi][ni][r] + bl[ni]);
            }
            #pragma unroll
            for (int j = 0; j < 4; ++j) {
                int flat = lane + j * 64;
                int r32 = flat >> 3, ch = flat & 7;
                int grow = m0 + part * 32 + r32;
                if (!iskv || grow < NN_)
                    *reinterpret_cast<int4*>(outp + (size_t)grow * ldo + coff + ch * 8) =
                        *reinterpret_cast<const int4*>(&Sh[w][r32][ch * 8]);
            }
        }
    }
}

// ---------------- generic 64x64 MFMA GEMM (G5), reg-prefetch ----------------
template<bool RELU>
__global__ __launch_bounds__(256) void gemm64(
    const ushort_t* __restrict__ Asrc, const ushort_t* __restrict__ Bt,
    const float* __restrict__ biasN, ushort_t* __restrict__ out,
    int M, int Ksteps, int lda, int ldb, int ldo,
    const int* __restrict__ arid) {
    __shared__ ushort_t Al[64][40];
    __shared__ ushort_t Bl[64][40];
    const int tid = threadIdx.x;
    const int m0 = blockIdx.x * 64, n0 = blockIdx.y * 64;
    const int lane = tid & 63, w = tid >> 6, wm = w >> 1, wn = w & 1;
    const int srow = tid >> 2, sch = tid & 3;
    const int gmi = m0 + srow;
    const bool valid = gmi < M;
    const int gr = valid ? (arid ? arid[gmi] : gmi) : 0;
    const ushort_t* arow = Asrc + (size_t)gr * lda + sch * 8;
    const ushort_t* brow = Bt + (size_t)(n0 + srow) * ldb + sch * 8;

    int4 aP = {0, 0, 0, 0};
    if (valid) aP = *reinterpret_cast<const int4*>(arow);
    int4 bP = *reinterpret_cast<const int4*>(brow);

    f32x4 acc[2][2] = {};
    for (int s = 0; s < Ksteps; ++s) {
        __syncthreads();
        *reinterpret_cast<int4*>(&Al[srow][sch * 8]) = aP;
        *reinterpret_cast<int4*>(&Bl[srow][sch * 8]) = bP;
        if (s + 1 < Ksteps) {
            if (valid) aP = *reinterpret_cast<const int4*>(arow + (s + 1) * 32);
            bP = *reinterpret_cast<const int4*>(brow + (s + 1) * 32);
        }
        __syncthreads();
        const int lr = lane & 15, lk = (lane >> 4) * 8;
        bf16x8 a0 = *reinterpret_cast<const bf16x8*>(&Al[wm * 32 + lr][lk]);
        bf16x8 a1 = *reinterpret_cast<const bf16x8*>(&Al[wm * 32 + 16 + lr][lk]);
        bf16x8 b0 = *reinterpret_cast<const bf16x8*>(&Bl[wn * 32 + lr][lk]);
        bf16x8 b1 = *reinterpret_cast<const bf16x8*>(&Bl[wn * 32 + 16 + lr][lk]);
        acc[0][0] = mfma16(a0, b0, acc[0][0]);
        acc[0][1] = mfma16(a0, b1, acc[0][1]);
        acc[1][0] = mfma16(a1, b0, acc[1][0]);
        acc[1][1] = mfma16(a1, b1, acc[1][1]);
    }
    #pragma unroll
    for (int mi = 0; mi < 2; ++mi)
        #pragma unroll
        for (int ni = 0; ni < 2; ++ni)
            #pragma unroll
            for (int r = 0; r < 4; ++r) {
                int m = m0 + wm * 32 + mi * 16 + ((lane >> 4) << 2) + r;
                int n = n0 + wn * 32 + ni * 16 + (lane & 15);
                if (m < M) {
                    float v = acc[mi][ni][r] + biasN[n];
                    if (RELU) v = fmaxf(v, 0.f);
                    out[(size_t)m * ldo + n] = f2bfu(v);
                }
            }
}

// ---------------- 32x256 GEMM + bias + residual + LayerNorm, A resident -----
__global__ __launch_bounds__(256) void gemm_ln(
    const ushort_t* __restrict__ A, const ushort_t* __restrict__ Bt,
    const float* __restrict__ biasN,
    const ushort_t* __restrict__ resmat, const int* __restrict__ residx, int rstride,
    const float* __restrict__ lng, const float* __restrict__ lnb,
    ushort_t* __restrict__ out, int M) {
    __shared__ union {
        struct { ushort_t Al[32][264]; ushort_t Bl[256][40]; } s;
        struct { float xr[32][260]; float mrow[32]; float rrow[32]; int sidx[32]; } e;
    } sm;
    const int tid = threadIdx.x;
    const int m0 = blockIdx.x * 32;
    const int lane = tid & 63, w = tid >> 6;
    const int lr = lane & 15, lk = (lane >> 4) * 8;

    #pragma unroll
    for (int j = 0; j < 4; ++j) {
        int flat = tid + j * 256;
        int row = flat >> 5, ch = flat & 31;
        *reinterpret_cast<int4*>(&sm.s.Al[row][ch * 8]) =
            *reinterpret_cast<const int4*>(A + (size_t)(m0 + row) * 256 + ch * 8);
    }
    const ushort_t* brow = Bt + (size_t)tid * 256;
    int4 bP[4];
    #pragma unroll
    for (int j = 0; j < 4; ++j) bP[j] = *reinterpret_cast<const int4*>(brow + j * 8);

    f32x4 acc[2][4] = {};
    for (int s = 0; s < 8; ++s) {
        __syncthreads();
        #pragma unroll
        for (int j = 0; j < 4; ++j)
            *reinterpret_cast<int4*>(&sm.s.Bl[tid][j * 8]) = bP[j];
        if (s < 7) {
            #pragma unroll
            for (int j = 0; j < 4; ++j)
                bP[j] = *reinterpret_cast<const int4*>(brow + (s + 1) * 32 + j * 8);
        }
        __syncthreads();
        bf16x8 a0 = *reinterpret_cast<const bf16x8*>(&sm.s.Al[lr][s * 32 + lk]);
        bf16x8 a1 = *reinterpret_cast<const bf16x8*>(&sm.s.Al[16 + lr][s * 32 + lk]);
        #pragma unroll
        for (int ni = 0; ni < 4; ++ni) {
            bf16x8 b = *reinterpret_cast<const bf16x8*>(&sm.s.Bl[w * 64 + ni * 16 + lr][lk]);
            acc[0][ni] = mfma16(a0, b, acc[0][ni]);
            acc[1][ni] = mfma16(a1, b, acc[1][ni]);
        }
    }
    __syncthreads();
    if (tid < 32) sm.e.sidx[tid] = residx ? residx[m0 + tid] : (m0 + tid) * rstride;
    #pragma unroll
    for (int mi = 0; mi < 2; ++mi)
        #pragma unroll
        for (int ni = 0; ni < 4; ++ni)
            #pragma unroll
            for (int r = 0; r < 4; ++r) {
                int rl = mi * 16 + ((lane >> 4) << 2) + r;
                int cl = w * 64 + ni * 16 + (lane & 15);
                sm.e.xr[rl][cl] = acc[mi][ni][r];
            }
    __syncthreads();
    {
        float bn = biasN[tid];
        for (int r = 0; r < 32; ++r)
            sm.e.xr[r][tid] += bn + bfu2f(resmat[(size_t)sm.e.sidx[r] * 256 + tid]);
    }
    __syncthreads();
    {
        for (int rr = w * 8; rr < w * 8 + 8; ++rr) {
            float4 v = *reinterpret_cast<const float4*>(&sm.e.xr[rr][lane * 4]);
            float s1 = v.x + v.y + v.z + v.w;
            float s2 = v.x * v.x + v.y * v.y + v.z * v.z + v.w * v.w;
            #pragma unroll
            for (int off = 32; off > 0; off >>= 1) {
                s1 += __shfl_xor(s1, off);
                s2 += __shfl_xor(s2, off);
            }
            if (lane == 0) {
                float m = s1 * (1.f / 256.f);
                float var = s2 * (1.f / 256.f) - m * m;
                sm.e.mrow[rr] = m;
                sm.e.rrow[rr] = rsqrtf(var + LN_EPS);
            }
        }
    }
    __syncthreads();
    {
        float g = lng[tid], b = lnb[tid];
        for (int r = 0; r < 32; ++r) {
            float v = (sm.e.xr[r][tid] - sm.e.mrow[r]) * sm.e.rrow[r] * g + b;
            out[(size_t)(m0 + r) * 256 + tid] = f2bfu(v);
        }
    }
}

// ---------------- attention: one wave per group (unchanged) ----------------
__global__ __launch_bounds__(256) void attn_wave(
    const ushort_t* __restrict__ q_all, int qld, int qoff, int qstride,
    const ushort_t* __restrict__ kv_all, int kvld, int koff, int voff,
    const int* __restrict__ kvidx, int ngroups, ushort_t* __restrict__ o_out) {
    __shared__ ushort_t KL[4][KVN][264];
    __shared__ ushort_t VL[4][KVN][264];
    const int w = threadIdx.x >> 6, lane = threadIdx.x & 63;
    const int g = blockIdx.x * 4 + w;
    if (g >= ngroups) return;

    int idx16 = 0;
    if (lane < KVN)
        idx16 = kvidx ? kvidx[g * KVN + lane] : g * SEQ + 1 + lane;

    float qv[4];
    {
        uint2 u = *reinterpret_cast<const uint2*>(
            q_all + (size_t)g * qstride * qld + qoff + lane * 4);
        qv[0] = bfu2f((ushort_t)(u.x & 0xffff));
        qv[1] = bfu2f((ushort_t)(u.x >> 16));
        qv[2] = bfu2f((ushort_t)(u.y & 0xffff));
        qv[3] = bfu2f((ushort_t)(u.y >> 16));
    }
    {
        const int r = lane & 15, qtr = lane >> 4;
        int rid = __shfl(idx16, r);
        const ushort_t* kb = kv_all + (size_t)rid * kvld + koff;
        const ushort_t* vb = kv_all + (size_t)rid * kvld + voff;
        #pragma unroll
        for (int j = 0; j < 8; ++j) {
            int c8 = (qtr * 8 + j) * 8;
            *reinterpret_cast<int4*>(&KL[w][r][c8]) = *reinterpret_cast<const int4*>(kb + c8);
            *reinterpret_cast<int4*>(&VL[w][r][c8]) = *reinterpret_cast<const int4*>(vb + c8);
        }
    }
    float att[KVN];
    #pragma unroll
    for (int k = 0; k < KVN; ++k) {
        uint2 u = *reinterpret_cast<const uint2*>(&KL[w][k][lane * 4]);
        float p = qv[0] * bfu2f((ushort_t)(u.x & 0xffff))
                + qv[1] * bfu2f((ushort_t)(u.x >> 16))
                + qv[2] * bfu2f((ushort_t)(u.y & 0xffff))
                + qv[3] * bfu2f((ushort_t)(u.y >> 16));
        p += __shfl_xor(p, 1);
        p += __shfl_xor(p, 2);
        p += __shfl_xor(p, 4);
        att[k] = p * 0.17677669529663687f;
    }
    float m = att[0];
    #pragma unroll
    for (int k = 1; k < KVN; ++k) m = fmaxf(m, att[k]);
    float sum = 0.f;
    #pragma unroll
    for (int k = 0; k < KVN; ++k) { att[k] = __expf(att[k] - m); sum += att[k]; }
    float inv = 1.f / sum;
    float o[4] = {0.f, 0.f, 0.f, 0.f};
    #pragma unroll
    for (int k = 0; k < KVN; ++k) {
        uint2 u = *reinterpret_cast<const uint2*>(&VL[w][k][lane * 4]);
        float a = att[k] * inv;
        o[0] += a * bfu2f((ushort_t)(u.x & 0xffff));
        o[1] += a * bfu2f((ushort_t)(u.x >> 16));
        o[2] += a * bfu2f((ushort_t)(u.y & 0xffff));
        o[3] += a * bfu2f((ushort_t)(u.y >> 16));
    }
    uint2 r;
    r.x = (unsigned)f2bfu(o[0]) | ((unsigned)f2bfu(o[1]) << 16);
    r.y = (unsigned)f2bfu(o[2]) | ((unsigned)f2bfu(o[3]) << 16);
    *reinterpret_cast<uint2*>(o_out + (size_t)g * 256 + lane * 4) = r;
}

// ---------------- output head (unchanged) ----------------
__global__ __launch_bounds__(64) void k_out(
    const ushort_t* __restrict__ h2, const float* __restrict__ W_out,
    const float* __restrict__ b_out, float* __restrict__ out) {
    const int b = blockIdx.x, j = threadIdx.x;
    __shared__ float xr[HDIM];
    for (int k = j; k < HDIM; k += 64) xr[k] = bfu2f(h2[(size_t)b * HDIM + k]);
    __syncthreads();
    float logit = -1e30f;
    if (j < OUTD) {
        float acc = b_out[j];
        for (int k = 0; k < HDIM; ++k) acc += xr[k] * W_out[k * OUTD + j];
        logit = acc;
    }
    float m = logit;
    #pragma unroll
    for (int off = 32; off > 0; off >>= 1) m = fmaxf(m, __shfl_xor(m, off));
    float e = (j < OUTD) ? __expf(logit - m) : 0.f;
    float s = e;
    #pragma unroll
    for (int off = 32; off > 0; off >>= 1) s += __shfl_xor(s, off);
    if (j < OUTD) out[(size_t)b * OUTD + j] = e / s;
}

extern "C" void kernel_launch(void* const* d_in, const int* in_sizes, int n_in,
                              void* d_out, int out_size, void* d_ws, size_t ws_size,
                              hipStream_t stream) {
    const float* nf    = (const float*)d_in[0];
    const int*   batch = (const int*)d_in[1];
    const int*   nbr2  = (const int*)d_in[2];
    const int*   nbr1  = (const int*)d_in[3];
    const float* W_in  = (const float*)d_in[4];
    const float* b_in  = (const float*)d_in[5];
    const float* Wqkv  = (const float*)d_in[6];
    const float* bqkv  = (const float*)d_in[7];
    const float* Wo    = (const float*)d_in[8];
    const float* bo    = (const float*)d_in[9];
    const float* Wf    = (const float*)d_in[10];
    const float* bf    = (const float*)d_in[11];
    const float* ln_g  = (const float*)d_in[12];
    const float* ln_b  = (const float*)d_in[13];
    const float* W_out = (const float*)d_in[14];
    const float* b_out = (const float*)d_in[15];
    float* out = (float*)d_out;
    char* ws = (char*)d_ws;

    ushort_t* hq   = (ushort_t*)(ws + OFF_HQ);
    ushort_t* kv0  = (ushort_t*)(ws + OFF_KV0);
    ushort_t* q0   = (ushort_t*)(ws + OFF_Q0);
    ushort_t* o0   = (ushort_t*)(ws + OFF_O0);
    ushort_t* ha   = (ushort_t*)(ws + OFF_HA);
    ushort_t* h1   = (ushort_t*)(ws + OFF_H1);
    ushort_t* qkv1 = (ushort_t*)(ws + OFF_QKV1);
    ushort_t* o1   = (ushort_t*)(ws + OFF_O1);
    ushort_t* ha2  = (ushort_t*)(ws + OFF_HA2);
    ushort_t* h2   = (ushort_t*)(ws + OFF_H2);
    const int* ids1 = (const int*)(ws + OFF_IDS);

    hipLaunchKernelGGL(k_prep, dim3(256, 13), dim3(256), 0, stream,
                       W_in, Wqkv, Wo, Wf, bqkv, batch, nbr2, ws);
    // fused: kv0 (1563 blocks) + hq,q0 (272 blocks)
    hipLaunchKernelGGL(k_fused, dim3(NKVBLK + NHQBLK), dim3(256), 0, stream,
                       nf, (const ushort_t*)(ws + OFF_WTIN), b_in,
                       (const ushort_t*)(ws + OFF_WKV0),
                       (const ushort_t*)(ws + OFF_WQ0), bqkv, ids1,
                       kv0, hq, q0);
    // A0: 17408 groups
    hipLaunchKernelGGL(attn_wave, dim3(N1 / 4), dim3(256), 0, stream,
                       q0, 256, 0, 1, kv0, 512, 0, 256, nbr1, N1, o0);
    // G3: ha = LN(o0 @ Wo0 + bo0 + hq)   (identity residual rows)
    hipLaunchKernelGGL(gemm_ln, dim3(544), dim3(256), 0, stream,
                       o0, (const ushort_t*)(ws + OFF_WO0), bo,
                       hq, (const int*)nullptr, 1, ln_g, ln_b, ha, N1);
    // G4: h1 = LN(ha @ Wf0 + bf0 + ha)
    hipLaunchKernelGGL(gemm_ln, dim3(544), dim3(256), 0, stream,
                       ha, (const ushort_t*)(ws + OFF_WF0), bf,
                       ha, (const int*)nullptr, 1, ln_g + 256, ln_b + 256, h1, N1);
    // G5: QKV1 = h1 @ [Wk1|Wv1|Wq1] + b
    hipLaunchKernelGGL((gemm64<false>), dim3(272, 12), dim3(256), 0, stream,
                       h1, (const ushort_t*)(ws + OFF_WKVQ1),
                       (const float*)(ws + OFF_B1), qkv1,
                       N1, 8, 256, 256, 768, (const int*)nullptr);
    // A1: 1024 groups
    hipLaunchKernelGGL(attn_wave, dim3(B_SZ / 4), dim3(256), 0, stream,
                       qkv1, 768, 512, 17, qkv1, 768, 0, 256,
                       (const int*)nullptr, B_SZ, o1);
    // G6: ha2 = LN(o1 @ Wo1 + bo1 + h1[17b])
    hipLaunchKernelGGL(gemm_ln, dim3(32), dim3(256), 0, stream,
                       o1, (const ushort_t*)(ws + OFF_WO1), bo + 256,
                       h1, (const int*)nullptr, 17, ln_g + 512, ln_b + 512, ha2, B_SZ);
    // G7: h2 = LN(ha2 @ Wf1 + bf1 + ha2)
    hipLaunchKernelGGL(gemm_ln, dim3(32), dim3(256), 0, stream,
                       ha2, (const ushort_t*)(ws + OFF_WF1), bf + 256,
                       ha2, (const int*)nullptr, 1, ln_g + 768, ln_b + 768, h2, B_SZ);
    hipLaunchKernelGGL(k_out, dim3(B_SZ), dim3(64), 0, stream,
                       h2, W_out, b_out, out);
}

// Round 7
// 288.420 us; speedup vs baseline: 1.6363x; 1.1689x over previous
//
#include <hip/hip_runtime.h>
#include <hip/hip_bf16.h>
#include <math.h>

typedef unsigned short ushort_t;
typedef __bf16 bf16x8 __attribute__((ext_vector_type(8)));
typedef float  f32x4  __attribute__((ext_vector_type(4)));

#define B_SZ   1024
#define SEQ    17
#define KVN    16
#define HDIM   256
#define NHEAD  8
#define DH     32
#define INF    150
#define OUTD   22
#define LN_EPS 1e-5f
#define N1     (B_SZ * SEQ)      // 17408
#define NN_    100000
#define NKVBLK 1563
#define NHQBLK 272               // 17408 / 64

// ---------------- workspace layout (bytes) ----------------
constexpr size_t SZ_H0    = (size_t)NN_ * 256 * 2;
constexpr size_t SZ_KV0   = (size_t)NN_ * 512 * 2;
constexpr size_t SZ_ROW   = (size_t)N1 * 256 * 2;
constexpr size_t OFF_HQ   = 0;
constexpr size_t OFF_KV0  = OFF_HQ + SZ_H0;
constexpr size_t OFF_QKV1 = OFF_KV0;                       // alias (KV0 dead after A0)
constexpr size_t OFF_O1   = OFF_QKV1 + (size_t)N1 * 768 * 2;
constexpr size_t OFF_H2   = OFF_O1 + (size_t)B_SZ * 256 * 2;
constexpr size_t OFF_Q0   = OFF_KV0 + SZ_KV0;
constexpr size_t OFF_O0   = OFF_Q0 + SZ_ROW;
constexpr size_t OFF_H1   = OFF_O0;                        // alias (o0 dead after FFN0 stage)
constexpr size_t OFF_IDS  = OFF_O0 + SZ_ROW;
constexpr size_t OFF_WTIN = OFF_IDS + (size_t)N1 * 4;
constexpr size_t OFF_WKV0 = OFF_WTIN + 256 * 160 * 2;
constexpr size_t OFF_WQ0  = OFF_WKV0 + 512 * 256 * 2;
constexpr size_t OFF_WKVQ1= OFF_WQ0 + 256 * 256 * 2;
constexpr size_t OFF_WO0  = OFF_WKVQ1 + 768 * 256 * 2;
constexpr size_t OFF_WF0  = OFF_WO0 + 256 * 256 * 2;
constexpr size_t OFF_WO1  = OFF_WF0 + 256 * 256 * 2;
constexpr size_t OFF_WF1  = OFF_WO1 + 256 * 256 * 2;
constexpr size_t OFF_B1   = OFF_WF1 + 256 * 256 * 2;

__device__ __forceinline__ ushort_t f2bfu(float x) {
    __hip_bfloat16 h = __float2bfloat16(x);
    return *reinterpret_cast<ushort_t*>(&h);
}
__device__ __forceinline__ float bfu2f(ushort_t u) {
    __hip_bfloat16 h;
    *reinterpret_cast<ushort_t*>(&h) = u;
    return __bfloat162float(h);
}
__device__ __forceinline__ f32x4 mfma16(bf16x8 a, bf16x8 b, f32x4 c) {
    return __builtin_amdgcn_mfma_f32_16x16x32_bf16(a, b, c, 0, 0, 0);
}

// ---------------- prep (unchanged) ----------------
__global__ __launch_bounds__(256) void k_prep(
    const float* __restrict__ W_in, const float* __restrict__ Wqkv,
    const float* __restrict__ Wo, const float* __restrict__ Wf,
    const float* __restrict__ bqkv,
    const int* __restrict__ batch, const int* __restrict__ nbr2,
    char* __restrict__ ws) {
    const int job = blockIdx.y;
    const int idx = blockIdx.x * 256 + threadIdx.x;
    if (job == 11) {
        if (idx < N1) {
            int b = idx / SEQ, s = idx % SEQ;
            ((int*)(ws + OFF_IDS))[idx] = (s == 0) ? batch[b] : nbr2[b * KVN + s - 1];
        }
        return;
    }
    if (job == 12) {
        if (idx < 768) ((float*)(ws + OFF_B1))[idx] = bqkv[768 + ((idx + 256) % 768)];
        return;
    }
    const float* src = nullptr; ushort_t* dst = nullptr;
    int Kpad = 256, Kvalid = 256;
    switch (job) {
        case 0:  src = W_in;           dst = (ushort_t*)(ws + OFF_WTIN); Kpad = 160; Kvalid = 150; break;
        case 1:  src = Wqkv + 65536;   dst = (ushort_t*)(ws + OFF_WKV0); break;
        case 2:  src = Wqkv + 131072;  dst = (ushort_t*)(ws + OFF_WKV0) + 65536; break;
        case 3:  src = Wqkv;           dst = (ushort_t*)(ws + OFF_WQ0); break;
        case 4:  src = Wqkv + 262144;  dst = (ushort_t*)(ws + OFF_WKVQ1); break;
        case 5:  src = Wqkv + 327680;  dst = (ushort_t*)(ws + OFF_WKVQ1) + 65536; break;
        case 6:  src = Wqkv + 196608;  dst = (ushort_t*)(ws + OFF_WKVQ1) + 131072; break;
        case 7:  src = Wo;             dst = (ushort_t*)(ws + OFF_WO0); break;
        case 8:  src = Wo + 65536;     dst = (ushort_t*)(ws + OFF_WO1); break;
        case 9:  src = Wf;             dst = (ushort_t*)(ws + OFF_WF0); break;
        case 10: src = Wf + 65536;     dst = (ushort_t*)(ws + OFF_WF1); break;
    }
    const int total = 256 * Kpad;
    if (idx >= total) return;
    int n = idx / Kpad, k = idx % Kpad;
    dst[idx] = (k < Kvalid) ? f2bfu(src[(size_t)k * 256 + n]) : (ushort_t)0;
}

// ============== fused: kv0 (blocks 0..1562) + hq/q0 (blocks 1563..1834) ======
// Barrier-free K-loops with manual depth-1 register prefetch of B fragments.
__global__ __launch_bounds__(256) void k_fused(
    const float* __restrict__ nf,
    const ushort_t* __restrict__ Wt_in, const float* __restrict__ b_in,
    const ushort_t* __restrict__ Wkv, const ushort_t* __restrict__ Wq,
    const float* __restrict__ bqkv, const int* __restrict__ ids1,
    ushort_t* __restrict__ kv0, ushort_t* __restrict__ hq,
    ushort_t* __restrict__ q0) {
    __shared__ ushort_t Ah[64 * 256];        // 32 KB; XOR-swizzled A tile
    __shared__ ushort_t Sh[4][32][72];       // 18.4 KB; wave-private epilogue bounce
    const int tid = threadIdx.x;
    const bool iskv = blockIdx.x < NKVBLK;
    const int m0 = (iskv ? blockIdx.x : blockIdx.x - NKVBLK) * 64;
    const int lane = tid & 63, w = tid >> 6;
    const int lr = lane & 15, q4 = lane >> 4, lk = q4 * 8;

    // ---- stage A: 64 rows x 160 cols f32->bf16 into Astage (aliases Ah) ----
    {
        ushort_t (*Astage)[168] = reinterpret_cast<ushort_t (*)[168]>(Ah);
        #pragma unroll
        for (int i = 0; i < 5; ++i) {
            int flat = tid + i * 256;
            int row = flat / 20, ch = flat % 20;
            int gm; bool valid;
            if (iskv) { gm = m0 + row; valid = gm < NN_; if (!valid) gm = 0; }
            else      { gm = ids1[m0 + row]; valid = true; }
            const float* ap = nf + (size_t)gm * INF + ch * 8;
            ushort_t tmp[8];
            if (valid && ch < 18) {
                #pragma unroll
                for (int j = 0; j < 4; ++j) {
                    float2 f = *reinterpret_cast<const float2*>(ap + j * 2);
                    tmp[j * 2] = f2bfu(f.x); tmp[j * 2 + 1] = f2bfu(f.y);
                }
            } else {
                #pragma unroll
                for (int j = 0; j < 8; ++j) {
                    int k = ch * 8 + j;
                    tmp[j] = (valid && k < INF) ? f2bfu(ap[j]) : (ushort_t)0;
                }
            }
            *reinterpret_cast<int4*>(&Astage[row][ch * 8]) = *reinterpret_cast<int4*>(tmp);
        }
    }
    __syncthreads();

    // ---- phase 1: acc = A @ W_in (K=160), barrier-free, prefetch depth 1 ----
    f32x4 acc[4][4] = {};
    {
        ushort_t (*Astage)[168] = reinterpret_cast<ushort_t (*)[168]>(Ah);
        bf16x8 bc[4];
        #pragma unroll
        for (int ni = 0; ni < 4; ++ni)
            bc[ni] = *reinterpret_cast<const bf16x8*>(
                Wt_in + (size_t)(w * 64 + ni * 16 + lr) * 160 + lk);
        #pragma unroll
        for (int s = 0; s < 5; ++s) {
            bf16x8 bn[4];
            if (s < 4) {
                #pragma unroll
                for (int ni = 0; ni < 4; ++ni)
                    bn[ni] = *reinterpret_cast<const bf16x8*>(
                        Wt_in + (size_t)(w * 64 + ni * 16 + lr) * 160 + (s + 1) * 32 + lk);
            }
            bf16x8 a[4];
            #pragma unroll
            for (int mi = 0; mi < 4; ++mi)
                a[mi] = *reinterpret_cast<const bf16x8*>(&Astage[mi * 16 + lr][s * 32 + lk]);
            #pragma unroll
            for (int mi = 0; mi < 4; ++mi)
                #pragma unroll
                for (int ni = 0; ni < 4; ++ni)
                    acc[mi][ni] = mfma16(a[mi], bc[ni], acc[mi][ni]);
            if (s < 4) {
                #pragma unroll
                for (int ni = 0; ni < 4; ++ni) bc[ni] = bn[ni];
            }
        }
    }
    __syncthreads();          // Astage reads done before Ah overwrite

    // ---- bias + relu -> Ah (XOR-swizzled) ----
    #pragma unroll
    for (int ni = 0; ni < 4; ++ni) {
        int col = w * 64 + ni * 16 + lr;
        float bb = b_in[col];
        #pragma unroll
        for (int mi = 0; mi < 4; ++mi)
            #pragma unroll
            for (int r = 0; r < 4; ++r) {
                int row = mi * 16 + q4 * 4 + r;
                Ah[row * 256 + (col ^ ((row & 7) << 3))] =
                    f2bfu(fmaxf(acc[mi][ni][r] + bb, 0.f));
            }
    }
    __syncthreads();

    if (!iskv) {   // persist gathered relu tile for G3 residual
        #pragma unroll
        for (int i = 0; i < 8; ++i) {
            int flat = tid + i * 256;
            int row = flat >> 5, ch = flat & 31;
            *reinterpret_cast<int4*>(hq + (size_t)(m0 + row) * 256 + ch * 8) =
                *reinterpret_cast<const int4*>(&Ah[row * 256 + (ch ^ (row & 7)) * 8]);
        }
    }

    // ---- phase 2: out = Ah @ B (K=256), barrier-free, prefetch depth 1 ----
    const int nh = iskv ? 2 : 1;
    for (int h = 0; h < nh; ++h) {
        const ushort_t* Bm = iskv ? (Wkv + (size_t)h * 256 * 256) : Wq;
        const float* bias = iskv ? (bqkv + 256 + h * 256) : bqkv;
        f32x4 acc2[4][4] = {};
        bf16x8 bc[4];
        #pragma unroll
        for (int ni = 0; ni < 4; ++ni)
            bc[ni] = *reinterpret_cast<const bf16x8*>(
                Bm + (size_t)(w * 64 + ni * 16 + lr) * 256 + lk);
        #pragma unroll
        for (int s = 0; s < 8; ++s) {
            bf16x8 bn[4];
            if (s < 7) {
                #pragma unroll
                for (int ni = 0; ni < 4; ++ni)
                    bn[ni] = *reinterpret_cast<const bf16x8*>(
                        Bm + (size_t)(w * 64 + ni * 16 + lr) * 256 + (s + 1) * 32 + lk);
            }
            bf16x8 a[4];
            #pragma unroll
            for (int mi = 0; mi < 4; ++mi) {
                int row = mi * 16 + lr;
                int chunk = (s * 4 + q4) ^ (row & 7);
                a[mi] = *reinterpret_cast<const bf16x8*>(&Ah[row * 256 + chunk * 8]);
            }
            #pragma unroll
            for (int mi = 0; mi < 4; ++mi)
                #pragma unroll
                for (int ni = 0; ni < 4; ++ni)
                    acc2[mi][ni] = mfma16(a[mi], bc[ni], acc2[mi][ni]);
            if (s < 7) {
                #pragma unroll
                for (int ni = 0; ni < 4; ++ni) bc[ni] = bn[ni];
            }
        }
        float bl[4];
        #pragma unroll
        for (int ni = 0; ni < 4; ++ni) bl[ni] = bias[w * 64 + ni * 16 + lr];
        ushort_t* outp = iskv ? kv0 : q0;
        const int ldo = iskv ? 512 : 256;
        const int coff = (iskv ? h * 256 : 0) + w * 64;
        #pragma unroll
        for (int part = 0; part < 2; ++part) {
            #pragma unroll
            for (int mi2 = 0; mi2 < 2; ++mi2) {
                int mi = part * 2 + mi2;
                #pragma unroll
                for (int ni = 0; ni < 4; ++ni)
                    #pragma unroll
                    for (int r = 0; r < 4; ++r)
                        Sh[w][mi2 * 16 + q4 * 4 + r][ni * 16 + lr] =
                            f2bfu(acc2[mi][ni][r] + bl[ni]);
            }
            #pragma unroll
            for (int j = 0; j < 4; ++j) {
                int flat = lane + j * 64;
                int r32 = flat >> 3, ch = flat & 7;
                int grow = m0 + part * 32 + r32;
                if (!iskv || grow < NN_)
                    *reinterpret_cast<int4*>(outp + (size_t)grow * ldo + coff + ch * 8) =
                        *reinterpret_cast<const int4*>(&Sh[w][r32][ch * 8]);
            }
        }
    }
}

// ======= k_ffn: fused {GEMM(W1)+bias+res+LN} -> {GEMM(W2)+bias+res+LN} =======
// 32-row tile. ha lives only in LDS. K-loops barrier-free with prefetch.
__global__ __launch_bounds__(256) void k_ffn(
    const ushort_t* __restrict__ Ain, const ushort_t* __restrict__ W1t,
    const float* __restrict__ b1,
    const ushort_t* __restrict__ resmat, int rstride,
    const float* __restrict__ lng1, const float* __restrict__ lnb1,
    const ushort_t* __restrict__ W2t, const float* __restrict__ b2,
    const float* __restrict__ lng2, const float* __restrict__ lnb2,
    ushort_t* __restrict__ out) {
    __shared__ ushort_t Al[32][264];          // 16.9 KB: A tile, then ha tile
    __shared__ float xr[32][260];             // 33.3 KB
    __shared__ float mrow[32], rrow[32];
    const int tid = threadIdx.x;
    const int m0 = blockIdx.x * 32;
    const int lane = tid & 63, w = tid >> 6;
    const int lr = lane & 15, q4 = lane >> 4, lk = q4 * 8;

    // stage A (o rows)
    #pragma unroll
    for (int j = 0; j < 4; ++j) {
        int flat = tid + j * 256;
        int row = flat >> 5, ch = flat & 31;
        *reinterpret_cast<int4*>(&Al[row][ch * 8]) =
            *reinterpret_cast<const int4*>(Ain + (size_t)(m0 + row) * 256 + ch * 8);
    }
    __syncthreads();

    f32x4 acc[2][4];
    #pragma unroll
    for (int g = 0; g < 2; ++g) {              // g=0: W1 pass, g=1: W2 pass
        const ushort_t* Wt = g ? W2t : W1t;
        #pragma unroll
        for (int mi = 0; mi < 2; ++mi)
            #pragma unroll
            for (int ni = 0; ni < 4; ++ni) acc[mi][ni] = f32x4{0.f, 0.f, 0.f, 0.f};
        bf16x8 bc[4];
        #pragma unroll
        for (int ni = 0; ni < 4; ++ni)
            bc[ni] = *reinterpret_cast<const bf16x8*>(
                Wt + (size_t)(w * 64 + ni * 16 + lr) * 256 + lk);
        #pragma unroll
        for (int s = 0; s < 8; ++s) {
            bf16x8 bn[4];
            if (s < 7) {
                #pragma unroll
                for (int ni = 0; ni < 4; ++ni)
                    bn[ni] = *reinterpret_cast<const bf16x8*>(
                        Wt + (size_t)(w * 64 + ni * 16 + lr) * 256 + (s + 1) * 32 + lk);
            }
            bf16x8 a0 = *reinterpret_cast<const bf16x8*>(&Al[lr][s * 32 + lk]);
            bf16x8 a1 = *reinterpret_cast<const bf16x8*>(&Al[16 + lr][s * 32 + lk]);
            #pragma unroll
            for (int ni = 0; ni < 4; ++ni) {
                acc[0][ni] = mfma16(a0, bc[ni], acc[0][ni]);
                acc[1][ni] = mfma16(a1, bc[ni], acc[1][ni]);
            }
            if (s < 7) {
                #pragma unroll
                for (int ni = 0; ni < 4; ++ni) bc[ni] = bn[ni];
            }
        }
        // acc -> xr
        #pragma unroll
        for (int mi = 0; mi < 2; ++mi)
            #pragma unroll
            for (int ni = 0; ni < 4; ++ni)
                #pragma unroll
                for (int r = 0; r < 4; ++r)
                    xr[mi * 16 + q4 * 4 + r][w * 64 + ni * 16 + lr] = acc[mi][ni][r];
        __syncthreads();
        // bias + residual (col pass)
        {
            float bb = g ? b2[tid] : b1[tid];
            if (g == 0) {
                for (int r = 0; r < 32; ++r)
                    xr[r][tid] += bb + bfu2f(resmat[(size_t)(m0 + r) * rstride * 256 + tid]);
            } else {
                for (int r = 0; r < 32; ++r)
                    xr[r][tid] += bb + bfu2f(Al[r][tid]);   // ha residual from LDS
            }
        }
        __syncthreads();
        // row stats: wave w handles rows w*8..w*8+7
        for (int rr = w * 8; rr < w * 8 + 8; ++rr) {
            float4 v = *reinterpret_cast<const float4*>(&xr[rr][lane * 4]);
            float s1 = v.x + v.y + v.z + v.w;
            float s2 = v.x * v.x + v.y * v.y + v.z * v.z + v.w * v.w;
            #pragma unroll
            for (int off = 32; off > 0; off >>= 1) {
                s1 += __shfl_xor(s1, off);
                s2 += __shfl_xor(s2, off);
            }
            if (lane == 0) {
                float m = s1 * (1.f / 256.f);
                float var = s2 * (1.f / 256.f) - m * m;
                mrow[rr] = m;
                rrow[rr] = rsqrtf(var + LN_EPS);
            }
        }
        __syncthreads();
        // normalize: g=0 -> ha into Al (bf16); g=1 -> out global
        if (g == 0) {
            float gg = lng1[tid], bb = lnb1[tid];
            for (int r = 0; r < 32; ++r)
                Al[r][tid] = f2bfu((xr[r][tid] - mrow[r]) * rrow[r] * gg + bb);
        } else {
            float gg = lng2[tid], bb = lnb2[tid];
            for (int r = 0; r < 32; ++r)
                out[(size_t)(m0 + r) * 256 + tid] =
                    f2bfu((xr[r][tid] - mrow[r]) * rrow[r] * gg + bb);
        }
        __syncthreads();
    }
}

// ======= k_qkv1: qkv1 = h1 @ [Wk1|Wv1|Wq1] + B1, barrier-free =======
__global__ __launch_bounds__(256) void k_qkv1(
    const ushort_t* __restrict__ h1, const ushort_t* __restrict__ Wt,
    const float* __restrict__ bias, ushort_t* __restrict__ outm) {
    __shared__ ushort_t Ah[64 * 256];
    __shared__ ushort_t Sh[4][32][72];
    const int tid = threadIdx.x;
    const int m0 = blockIdx.x * 64;
    const int lane = tid & 63, w = tid >> 6;
    const int lr = lane & 15, q4 = lane >> 4, lk = q4 * 8;

    // stage A (bf16) XOR-swizzled
    #pragma unroll
    for (int i = 0; i < 8; ++i) {
        int flat = tid + i * 256;
        int row = flat >> 5, ch = flat & 31;
        *reinterpret_cast<int4*>(&Ah[row * 256 + ((ch ^ (row & 7)) * 8)]) =
            *reinterpret_cast<const int4*>(h1 + (size_t)(m0 + row) * 256 + ch * 8);
    }
    __syncthreads();

    for (int p = 0; p < 3; ++p) {
        f32x4 acc[4][4] = {};
        bf16x8 bc[4];
        #pragma unroll
        for (int ni = 0; ni < 4; ++ni)
            bc[ni] = *reinterpret_cast<const bf16x8*>(
                Wt + (size_t)(p * 256 + w * 64 + ni * 16 + lr) * 256 + lk);
        #pragma unroll
        for (int s = 0; s < 8; ++s) {
            bf16x8 bn[4];
            if (s < 7) {
                #pragma unroll
                for (int ni = 0; ni < 4; ++ni)
                    bn[ni] = *reinterpret_cast<const bf16x8*>(
                        Wt + (size_t)(p * 256 + w * 64 + ni * 16 + lr) * 256 + (s + 1) * 32 + lk);
            }
            bf16x8 a[4];
            #pragma unroll
            for (int mi = 0; mi < 4; ++mi) {
                int row = mi * 16 + lr;
                int chunk = (s * 4 + q4) ^ (row & 7);
                a[mi] = *reinterpret_cast<const bf16x8*>(&Ah[row * 256 + chunk * 8]);
            }
            #pragma unroll
            for (int mi = 0; mi < 4; ++mi)
                #pragma unroll
                for (int ni = 0; ni < 4; ++ni)
                    acc[mi][ni] = mfma16(a[mi], bc[ni], acc[mi][ni]);
            if (s < 7) {
                #pragma unroll
                for (int ni = 0; ni < 4; ++ni) bc[ni] = bn[ni];
            }
        }
        float bl[4];
        #pragma unroll
        for (int ni = 0; ni < 4; ++ni) bl[ni] = bias[p * 256 + w * 64 + ni * 16 + lr];
        const int coff = p * 256 + w * 64;
        #pragma unroll
        for (int part = 0; part < 2; ++part) {
            #pragma unroll
            for (int mi2 = 0; mi2 < 2; ++mi2) {
                int mi = part * 2 + mi2;
                #pragma unroll
                for (int ni = 0; ni < 4; ++ni)
                    #pragma unroll
                    for (int r = 0; r < 4; ++r)
                        Sh[w][mi2 * 16 + q4 * 4 + r][ni * 16 + lr] =
                            f2bfu(acc[mi][ni][r] + bl[ni]);
            }
            #pragma unroll
            for (int j = 0; j < 4; ++j) {
                int flat = lane + j * 64;
                int r32 = flat >> 3, ch = flat & 7;
                int grow = m0 + part * 32 + r32;
                *reinterpret_cast<int4*>(outm + (size_t)grow * 768 + coff + ch * 8) =
                    *reinterpret_cast<const int4*>(&Sh[w][r32][ch * 8]);
            }
        }
    }
}

// ---------------- attention: one wave per group (unchanged) ----------------
__global__ __launch_bounds__(256) void attn_wave(
    const ushort_t* __restrict__ q_all, int qld, int qoff, int qstride,
    const ushort_t* __restrict__ kv_all, int kvld, int koff, int voff,
    const int* __restrict__ kvidx, int ngroups, ushort_t* __restrict__ o_out) {
    __shared__ ushort_t KL[4][KVN][264];
    __shared__ ushort_t VL[4][KVN][264];
    const int w = threadIdx.x >> 6, lane = threadIdx.x & 63;
    const int g = blockIdx.x * 4 + w;
    if (g >= ngroups) return;

    int idx16 = 0;
    if (lane < KVN)
        idx16 = kvidx ? kvidx[g * KVN + lane] : g * SEQ + 1 + lane;

    float qv[4];
    {
        uint2 u = *reinterpret_cast<const uint2*>(
            q_all + (size_t)g * qstride * qld + qoff + lane * 4);
        qv[0] = bfu2f((ushort_t)(u.x & 0xffff));
        qv[1] = bfu2f((ushort_t)(u.x >> 16));
        qv[2] = bfu2f((ushort_t)(u.y & 0xffff));
        qv[3] = bfu2f((ushort_t)(u.y >> 16));
    }
    {
        const int r = lane & 15, qtr = lane >> 4;
        int rid = __shfl(idx16, r);
        const ushort_t* kb = kv_all + (size_t)rid * kvld + koff;
        const ushort_t* vb = kv_all + (size_t)rid * kvld + voff;
        #pragma unroll
        for (int j = 0; j < 8; ++j) {
            int c8 = (qtr * 8 + j) * 8;
            *reinterpret_cast<int4*>(&KL[w][r][c8]) = *reinterpret_cast<const int4*>(kb + c8);
            *reinterpret_cast<int4*>(&VL[w][r][c8]) = *reinterpret_cast<const int4*>(vb + c8);
        }
    }
    float att[KVN];
    #pragma unroll
    for (int k = 0; k < KVN; ++k) {
        uint2 u = *reinterpret_cast<const uint2*>(&KL[w][k][lane * 4]);
        float p = qv[0] * bfu2f((ushort_t)(u.x & 0xffff))
                + qv[1] * bfu2f((ushort_t)(u.x >> 16))
                + qv[2] * bfu2f((ushort_t)(u.y & 0xffff))
                + qv[3] * bfu2f((ushort_t)(u.y >> 16));
        p += __shfl_xor(p, 1);
        p += __shfl_xor(p, 2);
        p += __shfl_xor(p, 4);
        att[k] = p * 0.17677669529663687f;
    }
    float m = att[0];
    #pragma unroll
    for (int k = 1; k < KVN; ++k) m = fmaxf(m, att[k]);
    float sum = 0.f;
    #pragma unroll
    for (int k = 0; k < KVN; ++k) { att[k] = __expf(att[k] - m); sum += att[k]; }
    float inv = 1.f / sum;
    float o[4] = {0.f, 0.f, 0.f, 0.f};
    #pragma unroll
    for (int k = 0; k < KVN; ++k) {
        uint2 u = *reinterpret_cast<const uint2*>(&VL[w][k][lane * 4]);
        float a = att[k] * inv;
        o[0] += a * bfu2f((ushort_t)(u.x & 0xffff));
        o[1] += a * bfu2f((ushort_t)(u.x >> 16));
        o[2] += a * bfu2f((ushort_t)(u.y & 0xffff));
        o[3] += a * bfu2f((ushort_t)(u.y >> 16));
    }
    uint2 r;
    r.x = (unsigned)f2bfu(o[0]) | ((unsigned)f2bfu(o[1]) << 16);
    r.y = (unsigned)f2bfu(o[2]) | ((unsigned)f2bfu(o[3]) << 16);
    *reinterpret_cast<uint2*>(o_out + (size_t)g * 256 + lane * 4) = r;
}

// ---------------- output head (unchanged) ----------------
__global__ __launch_bounds__(64) void k_out(
    const ushort_t* __restrict__ h2, const float* __restrict__ W_out,
    const float* __restrict__ b_out, float* __restrict__ out) {
    const int b = blockIdx.x, j = threadIdx.x;
    __shared__ float xr[HDIM];
    for (int k = j; k < HDIM; k += 64) xr[k] = bfu2f(h2[(size_t)b * HDIM + k]);
    __syncthreads();
    float logit = -1e30f;
    if (j < OUTD) {
        float acc = b_out[j];
        for (int k = 0; k < HDIM; ++k) acc += xr[k] * W_out[k * OUTD + j];
        logit = acc;
    }
    float m = logit;
    #pragma unroll
    for (int off = 32; off > 0; off >>= 1) m = fmaxf(m, __shfl_xor(m, off));
    float e = (j < OUTD) ? __expf(logit - m) : 0.f;
    float s = e;
    #pragma unroll
    for (int off = 32; off > 0; off >>= 1) s += __shfl_xor(s, off);
    if (j < OUTD) out[(size_t)b * OUTD + j] = e / s;
}

extern "C" void kernel_launch(void* const* d_in, const int* in_sizes, int n_in,
                              void* d_out, int out_size, void* d_ws, size_t ws_size,
                              hipStream_t stream) {
    const float* nf    = (const float*)d_in[0];
    const int*   batch = (const int*)d_in[1];
    const int*   nbr2  = (const int*)d_in[2];
    const int*   nbr1  = (const int*)d_in[3];
    const float* W_in  = (const float*)d_in[4];
    const float* b_in  = (const float*)d_in[5];
    const float* Wqkv  = (const float*)d_in[6];
    const float* bqkv  = (const float*)d_in[7];
    const float* Wo    = (const float*)d_in[8];
    const float* bo    = (const float*)d_in[9];
    const float* Wf    = (const float*)d_in[10];
    const float* bf    = (const float*)d_in[11];
    const float* ln_g  = (const float*)d_in[12];
    const float* ln_b  = (const float*)d_in[13];
    const float* W_out = (const float*)d_in[14];
    const float* b_out = (const float*)d_in[15];
    float* out = (float*)d_out;
    char* ws = (char*)d_ws;

    ushort_t* hq   = (ushort_t*)(ws + OFF_HQ);
    ushort_t* kv0  = (ushort_t*)(ws + OFF_KV0);
    ushort_t* q0   = (ushort_t*)(ws + OFF_Q0);
    ushort_t* o0   = (ushort_t*)(ws + OFF_O0);
    ushort_t* h1   = (ushort_t*)(ws + OFF_H1);
    ushort_t* qkv1 = (ushort_t*)(ws + OFF_QKV1);
    ushort_t* o1   = (ushort_t*)(ws + OFF_O1);
    ushort_t* h2   = (ushort_t*)(ws + OFF_H2);
    const int* ids1 = (const int*)(ws + OFF_IDS);

    hipLaunchKernelGGL(k_prep, dim3(256, 13), dim3(256), 0, stream,
                       W_in, Wqkv, Wo, Wf, bqkv, batch, nbr2, ws);
    hipLaunchKernelGGL(k_fused, dim3(NKVBLK + NHQBLK), dim3(256), 0, stream,
                       nf, (const ushort_t*)(ws + OFF_WTIN), b_in,
                       (const ushort_t*)(ws + OFF_WKV0),
                       (const ushort_t*)(ws + OFF_WQ0), bqkv, ids1,
                       kv0, hq, q0);
    // A0
    hipLaunchKernelGGL(attn_wave, dim3(N1 / 4), dim3(256), 0, stream,
                       q0, 256, 0, 1, kv0, 512, 0, 256, nbr1, N1, o0);
    // FFN0: h1 = LN(LN(o0@Wo0+bo0+hq)@Wf0+bf0+same)
    hipLaunchKernelGGL(k_ffn, dim3(N1 / 32), dim3(256), 0, stream,
                       o0, (const ushort_t*)(ws + OFF_WO0), bo,
                       hq, 1, ln_g, ln_b,
                       (const ushort_t*)(ws + OFF_WF0), bf,
                       ln_g + 256, ln_b + 256, h1);
    // G5
    hipLaunchKernelGGL(k_qkv1, dim3(N1 / 64), dim3(256), 0, stream,
                       h1, (const ushort_t*)(ws + OFF_WKVQ1),
                       (const float*)(ws + OFF_B1), qkv1);
    // A1
    hipLaunchKernelGGL(attn_wave, dim3(B_SZ / 4), dim3(256), 0, stream,
                       qkv1, 768, 512, 17, qkv1, 768, 0, 256,
                       (const int*)nullptr, B_SZ, o1);
    // FFN1: h2 = LN(LN(o1@Wo1+bo1+h1[17b])@Wf1+bf1+same)
    hipLaunchKernelGGL(k_ffn, dim3(B_SZ / 32), dim3(256), 0, stream,
                       o1, (const ushort_t*)(ws + OFF_WO1), bo + 256,
                       h1, 17, ln_g + 512, ln_b + 512,
                       (const ushort_t*)(ws + OFF_WF1), bf + 256,
                       ln_g + 768, ln_b + 768, h2);
    hipLaunchKernelGGL(k_out, dim3(B_SZ), dim3(64), 0, stream,
                       h2, W_out, b_out, out);
}